// Round 5
// baseline (197.849 us; speedup 1.0000x reference)
//
#include <hip/hip_runtime.h>
#include <hip/hip_bf16.h>

typedef __bf16 bf16x8 __attribute__((ext_vector_type(8)));
typedef float  f32x4  __attribute__((ext_vector_type(4)));

// tanh-approx gelu (matches jax.nn.gelu approximate=True):
// gelu(x) = x * sigmoid(2*sqrt(2/pi)*(x + 0.044715 x^3))   [R2-proven numeric path]
__device__ __forceinline__ float gelu_tanh(float x) {
    float x2  = x * x;
    float t   = fmaf(0.044715f, x2, 1.0f);
    float arg = -1.5957691216057308f * x * t;   // -2*sqrt(2/pi)*x*(1+0.044715x^2)
    float e   = __expf(arg);
    return x * __builtin_amdgcn_rcpf(1.0f + e);
}

// w2t[u][k] = W2[k][u]  (bf16, K-contiguous per output column), 32768 elems
// w3t[d][u] = W3[u][d] for d<3 else 0 (bf16, padded to 16 cols), 4096 elems
__global__ void prep_weights(const float* __restrict__ W2, const float* __restrict__ W3,
                             __bf16* __restrict__ w2t, __bf16* __restrict__ w3t) {
    int idx = blockIdx.x * 256 + threadIdx.x;
    if (idx < 128 * 256) {
        int k = idx >> 8;
        int u = idx & 255;
        w2t[u * 128 + k] = (__bf16)W2[idx];
    } else if (idx < 128 * 256 + 16 * 256) {
        int t = idx - 128 * 256;
        int d = t >> 8;
        int u = t & 255;
        w3t[t] = (__bf16)(d < 3 ? W3[u * 3 + d] : 0.0f);
    }
}

__launch_bounds__(256, 4)
__global__ void edge_mlp(const float* __restrict__ y, const float* __restrict__ x,
                         const float* __restrict__ fy,
                         const int* __restrict__ nbr, const int* __restrict__ xidx,
                         const float* __restrict__ W1, const float* __restrict__ b1,
                         const __bf16* __restrict__ w2t, const float* __restrict__ b2,
                         const __bf16* __restrict__ w3t, const float* __restrict__ b3,
                         float* __restrict__ out, int E) {
    // g2s doubles as the layer-1 A-tile (first 16KB) and the gelu'd h2 tile (32KB)
    __shared__ __attribute__((aligned(16))) __bf16 g2s[64 * 256];
    __shared__ __attribute__((aligned(16))) float rels4[64][4];   // .w unused
    __shared__ float fys[64][3];
    __shared__ int   is[64];
    __shared__ float b2s[256];
    __shared__ float out3w[4][64][3];
    __shared__ float msg3[64][3];

    const int tid  = threadIdx.x;
    const int base = blockIdx.x * 64;

    // ---- stage edge tile + b2 ----
    if (tid < 64) {
        int g = base + tid;
        if (g < E) {
            int j = nbr[g];
            int i = xidx[g];
            is[tid] = i;
            rels4[tid][0] = y[j*3+0] - x[i*3+0];
            rels4[tid][1] = y[j*3+1] - x[i*3+1];
            rels4[tid][2] = y[j*3+2] - x[i*3+2];
            rels4[tid][3] = 0.0f;
            fys[tid][0] = fy[j*3+0];
            fys[tid][1] = fy[j*3+1];
            fys[tid][2] = fy[j*3+2];
        } else {
            is[tid] = -1;
            rels4[tid][0] = rels4[tid][1] = rels4[tid][2] = rels4[tid][3] = 0.0f;
            fys[tid][0] = fys[tid][1] = fys[tid][2] = 0.0f;
        }
    }
    b2s[tid] = b2[tid];
    __syncthreads();

    // ---- layer 1: h1 = gelu(rel @ W1 + b1) -> A-tile (swizzled bf16), R2 mapping ----
    {
        int u  = tid & 127;           // constant per thread
        int e0 = tid >> 7;
        float w0 = W1[u], w1 = W1[128 + u], w2 = W1[256 + u], bb = b1[u];
        #pragma unroll
        for (int r = 0; r < 32; ++r) {
            int e = e0 + 2 * r;
            f32x4 rel = *(const f32x4*)&rels4[e][0];   // one ds_read_b128
            float pre = fmaf(rel.x, w0, fmaf(rel.y, w1, fmaf(rel.z, w2, bb)));
            float g = gelu_tanh(pre);
            // swizzle: XOR touches bits 3-5 which live entirely in u (u < 128)
            g2s[e * 128 + (u ^ ((e & 7) << 3))] = (__bf16)g;
        }
    }
    __syncthreads();

    // ---- layer 2 MFMA: [64 x 128] @ [128 x 256]; wave w owns cols [64w, 64w+64) ----
    const int w    = tid >> 6;
    const int lane = tid & 63;
    const int l15  = lane & 15;
    const int h    = lane >> 4;
    const int amask = (l15 & 7) << 3;   // thread-constant A-read swizzle mask

    f32x4 acc[4][4];
    #pragma unroll
    for (int mt = 0; mt < 4; ++mt)
        #pragma unroll
        for (int nt = 0; nt < 4; ++nt)
            acc[mt][nt] = (f32x4){0.0f, 0.0f, 0.0f, 0.0f};

    #pragma unroll
    for (int ks = 0; ks < 4; ++ks) {
        int kb  = ks * 32 + h * 8;
        int xkb = kb ^ amask;           // row&7 == l15&7 for all mt
        bf16x8 af[4], bfr[4];
        #pragma unroll
        for (int mt = 0; mt < 4; ++mt) {
            int row = mt * 16 + l15;
            af[mt] = *(const bf16x8*)&g2s[row * 128 + xkb];
        }
        #pragma unroll
        for (int nt = 0; nt < 4; ++nt) {
            int u = w * 64 + nt * 16 + l15;
            bfr[nt] = *(const bf16x8*)&w2t[u * 128 + kb];   // L2-resident
        }
        #pragma unroll
        for (int mt = 0; mt < 4; ++mt)
            #pragma unroll
            for (int nt = 0; nt < 4; ++nt)
                acc[mt][nt] = __builtin_amdgcn_mfma_f32_16x16x32_bf16(af[mt], bfr[nt], acc[mt][nt], 0, 0, 0);
    }
    __syncthreads();   // A-tile reads complete; g2s may be overwritten

    // ---- epilogue: g2 = gelu(h2 + b2) -> LDS [e][u] (swizzled bf16), R2 numerics ----
    #pragma unroll
    for (int nt = 0; nt < 4; ++nt) {
        int u = w * 64 + nt * 16 + l15;
        float b2u = b2s[u];
        #pragma unroll
        for (int mt = 0; mt < 4; ++mt) {
            #pragma unroll
            for (int rg = 0; rg < 4; ++rg) {
                int e = mt * 16 + h * 4 + rg;
                float hh = acc[mt][nt][rg] + b2u;
                float g = gelu_tanh(hh);
                // e&7 == (h*4+rg)&7: mask constant under unroll; XOR lives in u
                g2s[e * 256 + (u ^ ((e & 7) << 3))] = (__bf16)g;
            }
        }
    }
    __syncthreads();

    // ---- layer 3 MFMA: [64 x 256] @ [256 x 16(pad 3)]; wave w does K-slice [64w, 64w+64) ----
    f32x4 acc3[4];
    #pragma unroll
    for (int mt = 0; mt < 4; ++mt) acc3[mt] = (f32x4){0.0f, 0.0f, 0.0f, 0.0f};

    #pragma unroll
    for (int ks = 0; ks < 2; ++ks) {
        int u0  = w * 64 + ks * 32 + h * 8;
        int xu0 = u0 ^ amask;          // e&7 == l15&7 for all mt
        bf16x8 b3f = *(const bf16x8*)&w3t[l15 * 256 + u0];
        #pragma unroll
        for (int mt = 0; mt < 4; ++mt) {
            int e = mt * 16 + l15;
            bf16x8 a3 = *(const bf16x8*)&g2s[e * 256 + xu0];
            acc3[mt] = __builtin_amdgcn_mfma_f32_16x16x32_bf16(a3, b3f, acc3[mt], 0, 0, 0);
        }
    }
    if (l15 < 3) {
        #pragma unroll
        for (int mt = 0; mt < 4; ++mt)
            #pragma unroll
            for (int rg = 0; rg < 4; ++rg)
                out3w[w][mt * 16 + h * 4 + rg][l15] = acc3[mt][rg];
    }
    __syncthreads();

    // ---- combine wave partials, apply b3 and f_y ----
    if (tid < 192) {
        int e = tid / 3, d = tid - 3 * (tid / 3);
        float s = out3w[0][e][d] + out3w[1][e][d] + out3w[2][e][d] + out3w[3][e][d];
        msg3[e][d] = (s + b3[d]) * fys[e][d];
    }
    __syncthreads();

    // ---- segmented sum over sorted x_index: one atomic triple per distinct i ----
    if (tid < 64) {
        int i = is[tid];
        bool leader = (i >= 0) && (tid == 0 || is[tid - 1] != i);
        if (leader) {
            float s0 = 0.0f, s1 = 0.0f, s2 = 0.0f;
            int j = tid;
            while (j < 64 && is[j] == i) {
                s0 += msg3[j][0]; s1 += msg3[j][1]; s2 += msg3[j][2]; ++j;
            }
            unsafeAtomicAdd(&out[i*3+0], s0);
            unsafeAtomicAdd(&out[i*3+1], s1);
            unsafeAtomicAdd(&out[i*3+2], s2);
        }
    }
}

// out[i] /= max(cnt_i, 1); cnt via binary search on sorted x_index
__global__ void finalize_div(float* __restrict__ out, const int* __restrict__ xidx,
                             int E, int nx) {
    int i = blockIdx.x * blockDim.x + threadIdx.x;
    if (i >= nx) return;
    int lo = 0, hi = E;
    while (lo < hi) { int mid = (lo + hi) >> 1; if (xidx[mid] < i) lo = mid + 1; else hi = mid; }
    int start = lo;
    hi = E;
    while (lo < hi) { int mid = (lo + hi) >> 1; if (xidx[mid] < i + 1) lo = mid + 1; else hi = mid; }
    int cnt = lo - start;
    float inv = 1.0f / (float)(cnt > 1 ? cnt : 1);
    out[i*3+0] *= inv;
    out[i*3+1] *= inv;
    out[i*3+2] *= inv;
}

extern "C" void kernel_launch(void* const* d_in, const int* in_sizes, int n_in,
                              void* d_out, int out_size, void* d_ws, size_t ws_size,
                              hipStream_t stream) {
    const float* y   = (const float*)d_in[0];
    const float* x   = (const float*)d_in[1];
    const float* fyp = (const float*)d_in[2];
    const int*   nbr = (const int*)d_in[3];
    const int*   xix = (const int*)d_in[4];
    const float* W1  = (const float*)d_in[5];
    const float* b1  = (const float*)d_in[6];
    const float* W2  = (const float*)d_in[7];
    const float* b2  = (const float*)d_in[8];
    const float* W3  = (const float*)d_in[9];
    const float* b3  = (const float*)d_in[10];
    float* out = (float*)d_out;

    int E  = in_sizes[3];
    int nx = in_sizes[1] / 3;
    __bf16* w2t = (__bf16*)d_ws;                       // 32768 bf16 = 64KB
    __bf16* w3t = (__bf16*)((char*)d_ws + 65536);      // 4096 bf16 = 8KB

    hipMemsetAsync(d_out, 0, (size_t)out_size * sizeof(float), stream);
    prep_weights<<<144, 256, 0, stream>>>(W2, W3, w2t, w3t);

    int ntiles = (E + 63) / 64;
    edge_mlp<<<ntiles, 256, 0, stream>>>(y, x, fyp, nbr, xix, W1, b1, w2t, b2, w3t, b3, out, E);

    finalize_div<<<(nx + 255) / 256, 256, 0, stream>>>(out, xix, E, nx);
}

// Round 7
// 169.130 us; speedup vs baseline: 1.1698x; 1.1698x over previous
//
#include <hip/hip_runtime.h>
#include <hip/hip_bf16.h>

typedef __bf16 bf16x8 __attribute__((ext_vector_type(8)));
typedef float  f32x4  __attribute__((ext_vector_type(4)));
typedef float  f32x16 __attribute__((ext_vector_type(16)));
typedef int    i32x4  __attribute__((ext_vector_type(4)));

// tanh-approx gelu (matches jax.nn.gelu approximate=True)  [R2/R5-proven numeric path]
__device__ __forceinline__ float gelu_tanh(float x) {
    float x2  = x * x;
    float t   = fmaf(0.044715f, x2, 1.0f);
    float arg = -1.5957691216057308f * x * t;   // -2*sqrt(2/pi)*x*(1+0.044715x^2)
    float e   = __expf(arg);
    return x * __builtin_amdgcn_rcpf(1.0f + e);
}

// two scalar RNE casts + bit assembly (value-identical to R5's scalar stores)
__device__ __forceinline__ unsigned int pack2bf(float a, float b) {
    unsigned short ua = __builtin_bit_cast(unsigned short, (__bf16)a);
    unsigned short ub = __builtin_bit_cast(unsigned short, (__bf16)b);
    return (unsigned int)ua | ((unsigned int)ub << 16);
}

// w2t[u][k] = W2[k][u]  (bf16, K-contiguous per output column), 32768 elems
// w3t[d][u] = W3[u][d] for d<3 else 0 (bf16, padded to 32 rows), 8192 elems
__global__ void prep_weights(const float* __restrict__ W2, const float* __restrict__ W3,
                             __bf16* __restrict__ w2t, __bf16* __restrict__ w3t) {
    int idx = blockIdx.x * 256 + threadIdx.x;
    if (idx < 128 * 256) {
        int k = idx >> 8;
        int u = idx & 255;
        w2t[u * 128 + k] = (__bf16)W2[idx];
    } else if (idx < 128 * 256 + 32 * 256) {
        int t = idx - 128 * 256;
        int d = t >> 8;
        int u = t & 255;
        w3t[t] = (__bf16)(d < 3 ? W3[u * 3 + d] : 0.0f);
    }
}

__launch_bounds__(256, 4)
__global__ void edge_mlp(const float* __restrict__ y, const float* __restrict__ x,
                         const float* __restrict__ fy,
                         const int* __restrict__ nbr, const int* __restrict__ xidx,
                         const float* __restrict__ W1, const float* __restrict__ b1,
                         const __bf16* __restrict__ w2t, const float* __restrict__ b2,
                         const __bf16* __restrict__ w3t, const float* __restrict__ b3,
                         float* __restrict__ out, int E) {
    __shared__ __attribute__((aligned(16))) __bf16 g2s[64 * 128];  // h1 tile only, 16 KB
    __shared__ float rels[64][3];
    __shared__ float fys[64][3];
    __shared__ int   is[64];
    __shared__ float b2s[256];
    __shared__ float out3w[4][64][3];
    __shared__ float msg3[64][3];

    const int tid  = threadIdx.x;
    const int base = blockIdx.x * 64;

    // ---- stage edge tile + b2 ----
    if (tid < 64) {
        int g = base + tid;
        if (g < E) {
            int j = nbr[g];
            int i = xidx[g];
            is[tid] = i;
            rels[tid][0] = y[j*3+0] - x[i*3+0];
            rels[tid][1] = y[j*3+1] - x[i*3+1];
            rels[tid][2] = y[j*3+2] - x[i*3+2];
            fys[tid][0] = fy[j*3+0];
            fys[tid][1] = fy[j*3+1];
            fys[tid][2] = fy[j*3+2];
        } else {
            is[tid] = -1;
            rels[tid][0] = rels[tid][1] = rels[tid][2] = 0.0f;
            fys[tid][0] = fys[tid][1] = fys[tid][2] = 0.0f;
        }
    }
    b2s[tid] = b2[tid];
    __syncthreads();

    // ---- layer 1: h1 = gelu(rel @ W1 + b1) -> A-tile (swizzled bf16), R2-exact ----
    {
        int u  = tid & 127;           // constant per thread
        int e0 = tid >> 7;
        float w0 = W1[u], w1 = W1[128 + u], w2 = W1[256 + u], bb = b1[u];
        #pragma unroll
        for (int r = 0; r < 32; ++r) {
            int e = e0 + 2 * r;
            float pre = fmaf(rels[e][0], w0, fmaf(rels[e][1], w1, fmaf(rels[e][2], w2, bb)));
            float g = gelu_tanh(pre);
            g2s[e * 128 + (u ^ ((e & 7) << 3))] = (__bf16)g;
        }
    }
    __syncthreads();

    // ---- layer 2 MFMA (operand-swapped, 32x32x16): C = h2^T tiles [u][e] ----
    // wave w owns u in [64w, 64w+64); e-tiles et2*32 cover all 64 edges
    const int w    = tid >> 6;
    const int lane = tid & 63;
    const int l31  = lane & 31;
    const int b    = lane >> 5;

    f32x16 acc[2][2];   // [ut2][et2]
    #pragma unroll
    for (int ut2 = 0; ut2 < 2; ++ut2)
        #pragma unroll
        for (int et2 = 0; et2 < 2; ++et2)
            #pragma unroll
            for (int q = 0; q < 16; ++q)
                acc[ut2][et2][q] = 0.0f;

    #pragma unroll
    for (int kt = 0; kt < 8; ++kt) {
        int kc = kt * 16 + b * 8;
        bf16x8 bfrg[2], afrg[2];
        #pragma unroll
        for (int et2 = 0; et2 < 2; ++et2) {
            int row = et2 * 32 + l31;                       // row = edge e (B-col)
            bfrg[et2] = *(const bf16x8*)&g2s[row * 128 + (kc ^ ((row & 7) << 3))];
        }
        #pragma unroll
        for (int ut2 = 0; ut2 < 2; ++ut2) {
            int u = (2 * w + ut2) * 32 + l31;               // A-row = u
            afrg[ut2] = *(const bf16x8*)&w2t[u * 128 + kc]; // L2-resident
        }
        #pragma unroll
        for (int ut2 = 0; ut2 < 2; ++ut2)
            #pragma unroll
            for (int et2 = 0; et2 < 2; ++et2)
                acc[ut2][et2] = __builtin_amdgcn_mfma_f32_32x32x16_bf16(
                    afrg[ut2], bfrg[et2], acc[ut2][et2], 0, 0, 0);
    }
    // no barrier: g2s is never overwritten

    // ---- epilogue in-register: g2 = gelu(h2 + b2), pack to bf16 pairs ----
    // C layout (32x32): col=e=l31, row u_off = (reg&3) + 8*(reg>>2) + 4*b
    unsigned int pk[2][2][8];
    #pragma unroll
    for (int ut2 = 0; ut2 < 2; ++ut2) {
        int u0 = (2 * w + ut2) * 32 + 4 * b;
        f32x4 b2q[4];
        #pragma unroll
        for (int g = 0; g < 4; ++g)
            b2q[g] = *(const f32x4*)&b2s[u0 + 8 * g];
        #pragma unroll
        for (int et2 = 0; et2 < 2; ++et2) {
            #pragma unroll
            for (int g = 0; g < 4; ++g) {
                float g0 = gelu_tanh(acc[ut2][et2][4*g+0] + b2q[g][0]);
                float g1 = gelu_tanh(acc[ut2][et2][4*g+1] + b2q[g][1]);
                float g2 = gelu_tanh(acc[ut2][et2][4*g+2] + b2q[g][2]);
                float g3 = gelu_tanh(acc[ut2][et2][4*g+3] + b2q[g][3]);
                pk[ut2][et2][2*g+0] = pack2bf(g0, g1);
                pk[ut2][et2][2*g+1] = pack2bf(g2, g3);
            }
        }
    }

    // ---- layer 3 MFMA (32x32x16): C2[d][e] partial over wave's u-slice ----
    // B-frag assembled from pk; half-wave exchange via __shfl_xor(..., 32)
    // b=0 lane needs partner's words 4ki+{0,1}; b=1 lane needs partner's 4ki+{2,3}
    f32x16 acc3[2];
    #pragma unroll
    for (int et2 = 0; et2 < 2; ++et2)
        #pragma unroll
        for (int q = 0; q < 16; ++q)
            acc3[et2][q] = 0.0f;

    #pragma unroll
    for (int kt = 0; kt < 4; ++kt) {
        const int ut2 = kt >> 1, ki = kt & 1;
        bf16x8 a3 = *(const bf16x8*)&w3t[l31 * 256 + w * 64 + kt * 16 + b * 8];
        #pragma unroll
        for (int et2 = 0; et2 < 2; ++et2) {
            unsigned int w0_ = pk[ut2][et2][4*ki + 0];
            unsigned int w1_ = pk[ut2][et2][4*ki + 1];
            unsigned int w2_ = pk[ut2][et2][4*ki + 2];
            unsigned int w3_ = pk[ut2][et2][4*ki + 3];
            // send what the partner needs; receive what we need (lanes l <-> l^32)
            unsigned int send0 = b ? w0_ : w2_;
            unsigned int send1 = b ? w1_ : w3_;
            unsigned int rec0 = (unsigned int)__shfl_xor((int)send0, 32, 64);
            unsigned int rec1 = (unsigned int)__shfl_xor((int)send1, 32, 64);
            unsigned int f0 = b ? rec0 : w0_;   // k-offsets 16ki + (8b+0..1)
            unsigned int f1 = b ? rec1 : w1_;   //            16ki + (8b+2..3)
            unsigned int f2 = b ? w2_ : rec0;   //            16ki + (8b+4..5)
            unsigned int f3 = b ? w3_ : rec1;   //            16ki + (8b+6..7)
            i32x4 fri = { (int)f0, (int)f1, (int)f2, (int)f3 };
            bf16x8 bfr = __builtin_bit_cast(bf16x8, fri);
            acc3[et2] = __builtin_amdgcn_mfma_f32_32x32x16_bf16(a3, bfr, acc3[et2], 0, 0, 0);
        }
    }

    // valid outputs: rows d = reg (<3) for b==0 lanes; e = et2*32 + l31
    if (b == 0) {
        #pragma unroll
        for (int et2 = 0; et2 < 2; ++et2) {
            int e = et2 * 32 + l31;
            out3w[w][e][0] = acc3[et2][0];
            out3w[w][e][1] = acc3[et2][1];
            out3w[w][e][2] = acc3[et2][2];
        }
    }
    __syncthreads();

    // ---- combine wave partials, apply b3 and f_y ----
    if (tid < 192) {
        int e = tid / 3, d = tid - 3 * (tid / 3);
        float s = out3w[0][e][d] + out3w[1][e][d] + out3w[2][e][d] + out3w[3][e][d];
        msg3[e][d] = (s + b3[d]) * fys[e][d];
    }
    __syncthreads();

    // ---- segmented sum over sorted x_index: one atomic triple per distinct i ----
    if (tid < 64) {
        int i = is[tid];
        bool leader = (i >= 0) && (tid == 0 || is[tid - 1] != i);
        if (leader) {
            float s0 = 0.0f, s1 = 0.0f, s2 = 0.0f;
            int j = tid;
            while (j < 64 && is[j] == i) {
                s0 += msg3[j][0]; s1 += msg3[j][1]; s2 += msg3[j][2]; ++j;
            }
            unsafeAtomicAdd(&out[i*3+0], s0);
            unsafeAtomicAdd(&out[i*3+1], s1);
            unsafeAtomicAdd(&out[i*3+2], s2);
        }
    }
}

// out[i] /= max(cnt_i, 1); cnt via binary search on sorted x_index
__global__ void finalize_div(float* __restrict__ out, const int* __restrict__ xidx,
                             int E, int nx) {
    int i = blockIdx.x * blockDim.x + threadIdx.x;
    if (i >= nx) return;
    int lo = 0, hi = E;
    while (lo < hi) { int mid = (lo + hi) >> 1; if (xidx[mid] < i) lo = mid + 1; else hi = mid; }
    int start = lo;
    hi = E;
    while (lo < hi) { int mid = (lo + hi) >> 1; if (xidx[mid] < i + 1) lo = mid + 1; else hi = mid; }
    int cnt = lo - start;
    float inv = 1.0f / (float)(cnt > 1 ? cnt : 1);
    out[i*3+0] *= inv;
    out[i*3+1] *= inv;
    out[i*3+2] *= inv;
}

extern "C" void kernel_launch(void* const* d_in, const int* in_sizes, int n_in,
                              void* d_out, int out_size, void* d_ws, size_t ws_size,
                              hipStream_t stream) {
    const float* y   = (const float*)d_in[0];
    const float* x   = (const float*)d_in[1];
    const float* fyp = (const float*)d_in[2];
    const int*   nbr = (const int*)d_in[3];
    const int*   xix = (const int*)d_in[4];
    const float* W1  = (const float*)d_in[5];
    const float* b1  = (const float*)d_in[6];
    const float* W2  = (const float*)d_in[7];
    const float* b2  = (const float*)d_in[8];
    const float* W3  = (const float*)d_in[9];
    const float* b3  = (const float*)d_in[10];
    float* out = (float*)d_out;

    int E  = in_sizes[3];
    int nx = in_sizes[1] / 3;
    __bf16* w2t = (__bf16*)d_ws;                       // 32768 bf16 = 64KB
    __bf16* w3t = (__bf16*)((char*)d_ws + 65536);      // 8192 bf16 = 16KB

    hipMemsetAsync(d_out, 0, (size_t)out_size * sizeof(float), stream);
    prep_weights<<<160, 256, 0, stream>>>(W2, W3, w2t, w3t);

    int ntiles = (E + 63) / 64;
    edge_mlp<<<ntiles, 256, 0, stream>>>(y, x, fyp, nbr, xix, W1, b1, w2t, b2, w3t, b3, out, E);

    finalize_div<<<(nx + 255) / 256, 256, 0, stream>>>(out, xix, E, nx);
}

// Round 8
// 168.929 us; speedup vs baseline: 1.1712x; 1.0012x over previous
//
#include <hip/hip_runtime.h>
#include <hip/hip_bf16.h>

typedef __bf16 bf16x8 __attribute__((ext_vector_type(8)));
typedef float  f32x4  __attribute__((ext_vector_type(4)));
typedef float  f32x16 __attribute__((ext_vector_type(16)));
typedef int    i32x4  __attribute__((ext_vector_type(4)));

// tanh-approx gelu (matches jax.nn.gelu approximate=True)  [R2/R5-proven numeric path]
__device__ __forceinline__ float gelu_tanh(float x) {
    float x2  = x * x;
    float t   = fmaf(0.044715f, x2, 1.0f);
    float arg = -1.5957691216057308f * x * t;   // -2*sqrt(2/pi)*x*(1+0.044715x^2)
    float e   = __expf(arg);
    return x * __builtin_amdgcn_rcpf(1.0f + e);
}

// two scalar RNE casts + bit assembly (value-identical to R5's scalar stores)
__device__ __forceinline__ unsigned int pack2bf(float a, float b) {
    unsigned short ua = __builtin_bit_cast(unsigned short, (__bf16)a);
    unsigned short ub = __builtin_bit_cast(unsigned short, (__bf16)b);
    return (unsigned int)ua | ((unsigned int)ub << 16);
}

// w2t[u][k] = W2[k][u]  (bf16, K-contiguous per output column), 32768 elems
// w3t[d][u] = W3[u][d] for d<3 else 0 (bf16, padded to 32 rows), 8192 elems
__global__ void prep_weights(const float* __restrict__ W2, const float* __restrict__ W3,
                             __bf16* __restrict__ w2t, __bf16* __restrict__ w3t) {
    int idx = blockIdx.x * 256 + threadIdx.x;
    if (idx < 128 * 256) {
        int k = idx >> 8;
        int u = idx & 255;
        w2t[u * 128 + k] = (__bf16)W2[idx];
    } else if (idx < 128 * 256 + 32 * 256) {
        int t = idx - 128 * 256;
        int d = t >> 8;
        int u = t & 255;
        w3t[t] = (__bf16)(d < 3 ? W3[u * 3 + d] : 0.0f);
    }
}

__launch_bounds__(256, 4)
__global__ void edge_mlp(const float* __restrict__ y, const float* __restrict__ x,
                         const float* __restrict__ fy,
                         const int* __restrict__ nbr, const int* __restrict__ xidx,
                         const float* __restrict__ W1, const float* __restrict__ b1,
                         const __bf16* __restrict__ w2t, const float* __restrict__ b2,
                         const __bf16* __restrict__ w3t, const float* __restrict__ b3,
                         float* __restrict__ out, int E) {
    __shared__ __attribute__((aligned(16))) __bf16 g2s[64 * 128];  // h1 tile only, 16 KB
    __shared__ float rels[64][3];
    __shared__ float fys[64][3];
    __shared__ int   is[64];
    __shared__ float b2s[256];
    __shared__ float out3w[4][64][3];
    __shared__ float msg3[64][3];

    const int tid  = threadIdx.x;
    const int base = blockIdx.x * 64;

    // ---- stage edge tile + b2 ----
    if (tid < 64) {
        int g = base + tid;
        if (g < E) {
            int j = nbr[g];
            int i = xidx[g];
            is[tid] = i;
            rels[tid][0] = y[j*3+0] - x[i*3+0];
            rels[tid][1] = y[j*3+1] - x[i*3+1];
            rels[tid][2] = y[j*3+2] - x[i*3+2];
            fys[tid][0] = fy[j*3+0];
            fys[tid][1] = fy[j*3+1];
            fys[tid][2] = fy[j*3+2];
        } else {
            is[tid] = -1;
            rels[tid][0] = rels[tid][1] = rels[tid][2] = 0.0f;
            fys[tid][0] = fys[tid][1] = fys[tid][2] = 0.0f;
        }
    }
    b2s[tid] = b2[tid];
    __syncthreads();

    // ---- layer 1: h1 = gelu(rel @ W1 + b1) -> A-tile (swizzled bf16), R2-exact ----
    {
        int u  = tid & 127;           // constant per thread
        int e0 = tid >> 7;
        float w0 = W1[u], w1 = W1[128 + u], w2 = W1[256 + u], bb = b1[u];
        #pragma unroll
        for (int r = 0; r < 32; ++r) {
            int e = e0 + 2 * r;
            float pre = fmaf(rels[e][0], w0, fmaf(rels[e][1], w1, fmaf(rels[e][2], w2, bb)));
            float g = gelu_tanh(pre);
            g2s[e * 128 + (u ^ ((e & 7) << 3))] = (__bf16)g;
        }
    }
    __syncthreads();

    // ---- layer 2 MFMA (operand-swapped, 32x32x16), ut2-sliced to cap live regs ----
    // wave w owns u in [64w, 64w+64); slice ut2 covers u-rows [(2w+ut2)*32, +32)
    const int w    = tid >> 6;
    const int lane = tid & 63;
    const int l31  = lane & 31;
    const int b    = lane >> 5;

    unsigned int pk[2][2][8];   // [ut2][et2][word]; filled slice-by-slice

    #pragma unroll
    for (int ut2 = 0; ut2 < 2; ++ut2) {
        f32x16 acc[2];   // [et2] — lifetime limited to this slice
        #pragma unroll
        for (int et2 = 0; et2 < 2; ++et2)
            #pragma unroll
            for (int q = 0; q < 16; ++q)
                acc[et2][q] = 0.0f;

        #pragma unroll
        for (int kt = 0; kt < 8; ++kt) {
            int kc = kt * 16 + b * 8;
            bf16x8 bfrg[2];
            #pragma unroll
            for (int et2 = 0; et2 < 2; ++et2) {
                int row = et2 * 32 + l31;                       // row = edge e (B-col)
                bfrg[et2] = *(const bf16x8*)&g2s[row * 128 + (kc ^ ((row & 7) << 3))];
            }
            int u = (2 * w + ut2) * 32 + l31;                   // A-row = u
            bf16x8 afrg = *(const bf16x8*)&w2t[u * 128 + kc];   // L2-resident
            #pragma unroll
            for (int et2 = 0; et2 < 2; ++et2)
                acc[et2] = __builtin_amdgcn_mfma_f32_32x32x16_bf16(
                    afrg, bfrg[et2], acc[et2], 0, 0, 0);
        }

        // epilogue in-register: g2 = gelu(h2 + b2), pack to bf16 pairs
        // C layout (32x32): col=e=l31, row u_off = (reg&3) + 8*(reg>>2) + 4*b
        int u0 = (2 * w + ut2) * 32 + 4 * b;
        f32x4 b2q[4];
        #pragma unroll
        for (int g = 0; g < 4; ++g)
            b2q[g] = *(const f32x4*)&b2s[u0 + 8 * g];
        #pragma unroll
        for (int et2 = 0; et2 < 2; ++et2) {
            #pragma unroll
            for (int g = 0; g < 4; ++g) {
                float g0 = gelu_tanh(acc[et2][4*g+0] + b2q[g][0]);
                float g1 = gelu_tanh(acc[et2][4*g+1] + b2q[g][1]);
                float g2 = gelu_tanh(acc[et2][4*g+2] + b2q[g][2]);
                float g3 = gelu_tanh(acc[et2][4*g+3] + b2q[g][3]);
                pk[ut2][et2][2*g+0] = pack2bf(g0, g1);
                pk[ut2][et2][2*g+1] = pack2bf(g2, g3);
            }
        }
    }
    // no barrier: g2s is never overwritten

    // ---- layer 3 MFMA (32x32x16): C2[d][e] partial over wave's u-slice ----
    // B-frag assembled from pk; half-wave exchange via __shfl_xor(..., 32)
    f32x16 acc3[2];
    #pragma unroll
    for (int et2 = 0; et2 < 2; ++et2)
        #pragma unroll
        for (int q = 0; q < 16; ++q)
            acc3[et2][q] = 0.0f;

    #pragma unroll
    for (int kt = 0; kt < 4; ++kt) {
        const int ut2 = kt >> 1, ki = kt & 1;
        bf16x8 a3 = *(const bf16x8*)&w3t[l31 * 256 + w * 64 + kt * 16 + b * 8];
        #pragma unroll
        for (int et2 = 0; et2 < 2; ++et2) {
            unsigned int w0_ = pk[ut2][et2][4*ki + 0];
            unsigned int w1_ = pk[ut2][et2][4*ki + 1];
            unsigned int w2_ = pk[ut2][et2][4*ki + 2];
            unsigned int w3_ = pk[ut2][et2][4*ki + 3];
            // send what the partner needs; receive what we need (lanes l <-> l^32)
            unsigned int send0 = b ? w0_ : w2_;
            unsigned int send1 = b ? w1_ : w3_;
            unsigned int rec0 = (unsigned int)__shfl_xor((int)send0, 32, 64);
            unsigned int rec1 = (unsigned int)__shfl_xor((int)send1, 32, 64);
            unsigned int f0 = b ? rec0 : w0_;   // k-offsets 16ki + (8b+0..1)
            unsigned int f1 = b ? rec1 : w1_;   //            16ki + (8b+2..3)
            unsigned int f2 = b ? w2_ : rec0;   //            16ki + (8b+4..5)
            unsigned int f3 = b ? w3_ : rec1;   //            16ki + (8b+6..7)
            i32x4 fri = { (int)f0, (int)f1, (int)f2, (int)f3 };
            bf16x8 bfr = __builtin_bit_cast(bf16x8, fri);
            acc3[et2] = __builtin_amdgcn_mfma_f32_32x32x16_bf16(a3, bfr, acc3[et2], 0, 0, 0);
        }
    }

    // valid outputs: rows d = reg (<3) for b==0 lanes; e = et2*32 + l31
    if (b == 0) {
        #pragma unroll
        for (int et2 = 0; et2 < 2; ++et2) {
            int e = et2 * 32 + l31;
            out3w[w][e][0] = acc3[et2][0];
            out3w[w][e][1] = acc3[et2][1];
            out3w[w][e][2] = acc3[et2][2];
        }
    }
    __syncthreads();

    // ---- combine wave partials, apply b3 and f_y ----
    if (tid < 192) {
        int e = tid / 3, d = tid - 3 * (tid / 3);
        float s = out3w[0][e][d] + out3w[1][e][d] + out3w[2][e][d] + out3w[3][e][d];
        msg3[e][d] = (s + b3[d]) * fys[e][d];
    }
    __syncthreads();

    // ---- segmented sum over sorted x_index: one atomic triple per distinct i ----
    if (tid < 64) {
        int i = is[tid];
        bool leader = (i >= 0) && (tid == 0 || is[tid - 1] != i);
        if (leader) {
            float s0 = 0.0f, s1 = 0.0f, s2 = 0.0f;
            int j = tid;
            while (j < 64 && is[j] == i) {
                s0 += msg3[j][0]; s1 += msg3[j][1]; s2 += msg3[j][2]; ++j;
            }
            unsafeAtomicAdd(&out[i*3+0], s0);
            unsafeAtomicAdd(&out[i*3+1], s1);
            unsafeAtomicAdd(&out[i*3+2], s2);
        }
    }
}

// out[i] /= max(cnt_i, 1); cnt via binary search on sorted x_index
__global__ void finalize_div(float* __restrict__ out, const int* __restrict__ xidx,
                             int E, int nx) {
    int i = blockIdx.x * blockDim.x + threadIdx.x;
    if (i >= nx) return;
    int lo = 0, hi = E;
    while (lo < hi) { int mid = (lo + hi) >> 1; if (xidx[mid] < i) lo = mid + 1; else hi = mid; }
    int start = lo;
    hi = E;
    while (lo < hi) { int mid = (lo + hi) >> 1; if (xidx[mid] < i + 1) lo = mid + 1; else hi = mid; }
    int cnt = lo - start;
    float inv = 1.0f / (float)(cnt > 1 ? cnt : 1);
    out[i*3+0] *= inv;
    out[i*3+1] *= inv;
    out[i*3+2] *= inv;
}

extern "C" void kernel_launch(void* const* d_in, const int* in_sizes, int n_in,
                              void* d_out, int out_size, void* d_ws, size_t ws_size,
                              hipStream_t stream) {
    const float* y   = (const float*)d_in[0];
    const float* x   = (const float*)d_in[1];
    const float* fyp = (const float*)d_in[2];
    const int*   nbr = (const int*)d_in[3];
    const int*   xix = (const int*)d_in[4];
    const float* W1  = (const float*)d_in[5];
    const float* b1  = (const float*)d_in[6];
    const float* W2  = (const float*)d_in[7];
    const float* b2  = (const float*)d_in[8];
    const float* W3  = (const float*)d_in[9];
    const float* b3  = (const float*)d_in[10];
    float* out = (float*)d_out;

    int E  = in_sizes[3];
    int nx = in_sizes[1] / 3;
    __bf16* w2t = (__bf16*)d_ws;                       // 32768 bf16 = 64KB
    __bf16* w3t = (__bf16*)((char*)d_ws + 65536);      // 8192 bf16 = 16KB

    hipMemsetAsync(d_out, 0, (size_t)out_size * sizeof(float), stream);
    prep_weights<<<160, 256, 0, stream>>>(W2, W3, w2t, w3t);

    int ntiles = (E + 63) / 64;
    edge_mlp<<<ntiles, 256, 0, stream>>>(y, x, fyp, nbr, xix, W1, b1, w2t, b2, w3t, b3, out, E);

    finalize_div<<<(nx + 255) / 256, 256, 0, stream>>>(out, xix, E, nx);
}

// Round 9
// 160.177 us; speedup vs baseline: 1.2352x; 1.0546x over previous
//
#include <hip/hip_runtime.h>
#include <hip/hip_bf16.h>

typedef __bf16 bf16x8 __attribute__((ext_vector_type(8)));
typedef float  f32x4  __attribute__((ext_vector_type(4)));
typedef float  f32x2  __attribute__((ext_vector_type(2)));
typedef float  f32x16 __attribute__((ext_vector_type(16)));
typedef int    i32x4  __attribute__((ext_vector_type(4)));

// tanh-approx gelu (matches jax.nn.gelu approximate=True)  [R2/R5-proven numeric path]
__device__ __forceinline__ float gelu_tanh(float x) {
    float x2  = x * x;
    float t   = fmaf(0.044715f, x2, 1.0f);
    float arg = -1.5957691216057308f * x * t;   // -2*sqrt(2/pi)*x*(1+0.044715x^2)
    float e   = __expf(arg);
    return x * __builtin_amdgcn_rcpf(1.0f + e);
}

// paired gelu: identical per-component operation sequence to gelu_tanh
// (pk ops are per-component IEEE; __expf/rcp stay scalar per component)
__device__ __forceinline__ f32x2 gelu2(f32x2 x) {
    f32x2 x2 = x * x;                               // v_pk_mul_f32
    f32x2 t  = x2 * 0.044715f + 1.0f;               // v_pk_fma_f32 (contract), == fmaf(0.044715,x2,1)
    f32x2 a  = (x * -1.5957691216057308f) * t;      // (-c*x)*t, same assoc as scalar
    f32x2 e  = { __expf(a.x), __expf(a.y) };
    f32x2 d  = e + 1.0f;                            // v_pk_add_f32
    f32x2 r  = { __builtin_amdgcn_rcpf(d.x), __builtin_amdgcn_rcpf(d.y) };
    return x * r;                                   // v_pk_mul_f32
}

// two scalar RNE casts + bit assembly (value-identical to R5's scalar stores)
__device__ __forceinline__ unsigned int pack2bf(float a, float b) {
    unsigned short ua = __builtin_bit_cast(unsigned short, (__bf16)a);
    unsigned short ub = __builtin_bit_cast(unsigned short, (__bf16)b);
    return (unsigned int)ua | ((unsigned int)ub << 16);
}

// w2t[u][k] = W2[k][u]  (bf16, K-contiguous per output column), 32768 elems
// w3t[d][u] = W3[u][d] for d<3 else 0 (bf16, padded to 32 rows), 8192 elems
__global__ void prep_weights(const float* __restrict__ W2, const float* __restrict__ W3,
                             __bf16* __restrict__ w2t, __bf16* __restrict__ w3t) {
    int idx = blockIdx.x * 256 + threadIdx.x;
    if (idx < 128 * 256) {
        int k = idx >> 8;
        int u = idx & 255;
        w2t[u * 128 + k] = (__bf16)W2[idx];
    } else if (idx < 128 * 256 + 32 * 256) {
        int t = idx - 128 * 256;
        int d = t >> 8;
        int u = t & 255;
        w3t[t] = (__bf16)(d < 3 ? W3[u * 3 + d] : 0.0f);
    }
}

__launch_bounds__(256, 4)
__global__ void edge_mlp(const float* __restrict__ y, const float* __restrict__ x,
                         const float* __restrict__ fy,
                         const int* __restrict__ nbr, const int* __restrict__ xidx,
                         const float* __restrict__ W1, const float* __restrict__ b1,
                         const __bf16* __restrict__ w2t, const float* __restrict__ b2,
                         const __bf16* __restrict__ w3t, const float* __restrict__ b3,
                         float* __restrict__ out, int E) {
    __shared__ __attribute__((aligned(16))) __bf16 g2s[64 * 128];  // h1 tile only, 16 KB
    __shared__ float rels[64][3];
    __shared__ float fys[64][3];
    __shared__ int   is[64];
    __shared__ float b2s[256];
    __shared__ float out3w[4][64][3];
    __shared__ float msg3[64][3];

    const int tid  = threadIdx.x;
    const int base = blockIdx.x * 64;

    // ---- stage edge tile + b2 ----
    if (tid < 64) {
        int g = base + tid;
        if (g < E) {
            int j = nbr[g];
            int i = xidx[g];
            is[tid] = i;
            rels[tid][0] = y[j*3+0] - x[i*3+0];
            rels[tid][1] = y[j*3+1] - x[i*3+1];
            rels[tid][2] = y[j*3+2] - x[i*3+2];
            fys[tid][0] = fy[j*3+0];
            fys[tid][1] = fy[j*3+1];
            fys[tid][2] = fy[j*3+2];
        } else {
            is[tid] = -1;
            rels[tid][0] = rels[tid][1] = rels[tid][2] = 0.0f;
            fys[tid][0] = fys[tid][1] = fys[tid][2] = 0.0f;
        }
    }
    b2s[tid] = b2[tid];
    __syncthreads();

    // ---- layer 1: h1 = gelu(rel @ W1 + b1) -> A-tile (swizzled bf16) ----
    // paired gelu evaluation (edges e and e+2), scalar casts/stores as before
    {
        int u  = tid & 127;           // constant per thread
        int e0 = tid >> 7;
        float w0 = W1[u], w1 = W1[128 + u], w2 = W1[256 + u], bb = b1[u];
        #pragma unroll
        for (int r = 0; r < 32; r += 2) {
            int ea = e0 + 2 * r;
            int eb = e0 + 2 * (r + 1);
            float prea = fmaf(rels[ea][0], w0, fmaf(rels[ea][1], w1, fmaf(rels[ea][2], w2, bb)));
            float preb = fmaf(rels[eb][0], w0, fmaf(rels[eb][1], w1, fmaf(rels[eb][2], w2, bb)));
            f32x2 g = gelu2((f32x2){prea, preb});
            g2s[ea * 128 + (u ^ ((ea & 7) << 3))] = (__bf16)g.x;
            g2s[eb * 128 + (u ^ ((eb & 7) << 3))] = (__bf16)g.y;
        }
    }
    __syncthreads();

    // ---- layer 2 MFMA (operand-swapped, 32x32x16), ut2-sliced to cap live regs ----
    // wave w owns u in [64w, 64w+64); slice ut2 covers u-rows [(2w+ut2)*32, +32)
    const int w    = tid >> 6;
    const int lane = tid & 63;
    const int l31  = lane & 31;
    const int b    = lane >> 5;

    unsigned int pk[2][2][8];   // [ut2][et2][word]; filled slice-by-slice

    #pragma unroll
    for (int ut2 = 0; ut2 < 2; ++ut2) {
        f32x16 acc[2];   // [et2] — lifetime limited to this slice
        #pragma unroll
        for (int et2 = 0; et2 < 2; ++et2)
            #pragma unroll
            for (int q = 0; q < 16; ++q)
                acc[et2][q] = 0.0f;

        #pragma unroll
        for (int kt = 0; kt < 8; ++kt) {
            int kc = kt * 16 + b * 8;
            bf16x8 bfrg[2];
            #pragma unroll
            for (int et2 = 0; et2 < 2; ++et2) {
                int row = et2 * 32 + l31;                       // row = edge e (B-col)
                bfrg[et2] = *(const bf16x8*)&g2s[row * 128 + (kc ^ ((row & 7) << 3))];
            }
            int u = (2 * w + ut2) * 32 + l31;                   // A-row = u
            bf16x8 afrg = *(const bf16x8*)&w2t[u * 128 + kc];   // L2-resident
            #pragma unroll
            for (int et2 = 0; et2 < 2; ++et2)
                acc[et2] = __builtin_amdgcn_mfma_f32_32x32x16_bf16(
                    afrg, bfrg[et2], acc[et2], 0, 0, 0);
        }

        // epilogue in-register: g2 = gelu(h2 + b2), pack to bf16 pairs (paired gelu)
        // C layout (32x32): col=e=l31, row u_off = (reg&3) + 8*(reg>>2) + 4*b
        int u0 = (2 * w + ut2) * 32 + 4 * b;
        f32x4 b2q[4];
        #pragma unroll
        for (int g = 0; g < 4; ++g)
            b2q[g] = *(const f32x4*)&b2s[u0 + 8 * g];
        #pragma unroll
        for (int et2 = 0; et2 < 2; ++et2) {
            #pragma unroll
            for (int g = 0; g < 4; ++g) {
                f32x2 s01 = { acc[et2][4*g+0] + b2q[g][0], acc[et2][4*g+1] + b2q[g][1] };
                f32x2 s23 = { acc[et2][4*g+2] + b2q[g][2], acc[et2][4*g+3] + b2q[g][3] };
                f32x2 g01 = gelu2(s01);
                f32x2 g23 = gelu2(s23);
                pk[ut2][et2][2*g+0] = pack2bf(g01.x, g01.y);
                pk[ut2][et2][2*g+1] = pack2bf(g23.x, g23.y);
            }
        }
    }
    // no barrier: g2s is never overwritten

    // ---- layer 3 MFMA (32x32x16): C2[d][e] partial over wave's u-slice ----
    // B-frag assembled from pk; half-wave exchange via __shfl_xor(..., 32)
    f32x16 acc3[2];
    #pragma unroll
    for (int et2 = 0; et2 < 2; ++et2)
        #pragma unroll
        for (int q = 0; q < 16; ++q)
            acc3[et2][q] = 0.0f;

    #pragma unroll
    for (int kt = 0; kt < 4; ++kt) {
        const int ut2 = kt >> 1, ki = kt & 1;
        bf16x8 a3 = *(const bf16x8*)&w3t[l31 * 256 + w * 64 + kt * 16 + b * 8];
        #pragma unroll
        for (int et2 = 0; et2 < 2; ++et2) {
            unsigned int w0_ = pk[ut2][et2][4*ki + 0];
            unsigned int w1_ = pk[ut2][et2][4*ki + 1];
            unsigned int w2_ = pk[ut2][et2][4*ki + 2];
            unsigned int w3_ = pk[ut2][et2][4*ki + 3];
            // send what the partner needs; receive what we need (lanes l <-> l^32)
            unsigned int send0 = b ? w0_ : w2_;
            unsigned int send1 = b ? w1_ : w3_;
            unsigned int rec0 = (unsigned int)__shfl_xor((int)send0, 32, 64);
            unsigned int rec1 = (unsigned int)__shfl_xor((int)send1, 32, 64);
            unsigned int f0 = b ? rec0 : w0_;   // k-offsets 16ki + (8b+0..1)
            unsigned int f1 = b ? rec1 : w1_;   //            16ki + (8b+2..3)
            unsigned int f2 = b ? w2_ : rec0;   //            16ki + (8b+4..5)
            unsigned int f3 = b ? w3_ : rec1;   //            16ki + (8b+6..7)
            i32x4 fri = { (int)f0, (int)f1, (int)f2, (int)f3 };
            bf16x8 bfr = __builtin_bit_cast(bf16x8, fri);
            acc3[et2] = __builtin_amdgcn_mfma_f32_32x32x16_bf16(a3, bfr, acc3[et2], 0, 0, 0);
        }
    }

    // valid outputs: rows d = reg (<3) for b==0 lanes; e = et2*32 + l31
    if (b == 0) {
        #pragma unroll
        for (int et2 = 0; et2 < 2; ++et2) {
            int e = et2 * 32 + l31;
            out3w[w][e][0] = acc3[et2][0];
            out3w[w][e][1] = acc3[et2][1];
            out3w[w][e][2] = acc3[et2][2];
        }
    }
    __syncthreads();

    // ---- combine wave partials, apply b3 and f_y ----
    if (tid < 192) {
        int e = tid / 3, d = tid - 3 * (tid / 3);
        float s = out3w[0][e][d] + out3w[1][e][d] + out3w[2][e][d] + out3w[3][e][d];
        msg3[e][d] = (s + b3[d]) * fys[e][d];
    }
    __syncthreads();

    // ---- segmented sum over sorted x_index: one atomic triple per distinct i ----
    if (tid < 64) {
        int i = is[tid];
        bool leader = (i >= 0) && (tid == 0 || is[tid - 1] != i);
        if (leader) {
            float s0 = 0.0f, s1 = 0.0f, s2 = 0.0f;
            int j = tid;
            while (j < 64 && is[j] == i) {
                s0 += msg3[j][0]; s1 += msg3[j][1]; s2 += msg3[j][2]; ++j;
            }
            unsafeAtomicAdd(&out[i*3+0], s0);
            unsafeAtomicAdd(&out[i*3+1], s1);
            unsafeAtomicAdd(&out[i*3+2], s2);
        }
    }
}

// out[i] /= max(cnt_i, 1); cnt via binary search on sorted x_index
__global__ void finalize_div(float* __restrict__ out, const int* __restrict__ xidx,
                             int E, int nx) {
    int i = blockIdx.x * blockDim.x + threadIdx.x;
    if (i >= nx) return;
    int lo = 0, hi = E;
    while (lo < hi) { int mid = (lo + hi) >> 1; if (xidx[mid] < i) lo = mid + 1; else hi = mid; }
    int start = lo;
    hi = E;
    while (lo < hi) { int mid = (lo + hi) >> 1; if (xidx[mid] < i + 1) lo = mid + 1; else hi = mid; }
    int cnt = lo - start;
    float inv = 1.0f / (float)(cnt > 1 ? cnt : 1);
    out[i*3+0] *= inv;
    out[i*3+1] *= inv;
    out[i*3+2] *= inv;
}

extern "C" void kernel_launch(void* const* d_in, const int* in_sizes, int n_in,
                              void* d_out, int out_size, void* d_ws, size_t ws_size,
                              hipStream_t stream) {
    const float* y   = (const float*)d_in[0];
    const float* x   = (const float*)d_in[1];
    const float* fyp = (const float*)d_in[2];
    const int*   nbr = (const int*)d_in[3];
    const int*   xix = (const int*)d_in[4];
    const float* W1  = (const float*)d_in[5];
    const float* b1  = (const float*)d_in[6];
    const float* W2  = (const float*)d_in[7];
    const float* b2  = (const float*)d_in[8];
    const float* W3  = (const float*)d_in[9];
    const float* b3  = (const float*)d_in[10];
    float* out = (float*)d_out;

    int E  = in_sizes[3];
    int nx = in_sizes[1] / 3;
    __bf16* w2t = (__bf16*)d_ws;                       // 32768 bf16 = 64KB
    __bf16* w3t = (__bf16*)((char*)d_ws + 65536);      // 8192 bf16 = 16KB

    hipMemsetAsync(d_out, 0, (size_t)out_size * sizeof(float), stream);
    prep_weights<<<160, 256, 0, stream>>>(W2, W3, w2t, w3t);

    int ntiles = (E + 63) / 64;
    edge_mlp<<<ntiles, 256, 0, stream>>>(y, x, fyp, nbr, xix, W1, b1, w2t, b2, w3t, b3, out, E);

    finalize_div<<<(nx + 255) / 256, 256, 0, stream>>>(out, xix, E, nx);
}

// Round 11
// 158.471 us; speedup vs baseline: 1.2485x; 1.0108x over previous
//
#include <hip/hip_runtime.h>
#include <hip/hip_bf16.h>

typedef __bf16 bf16x8 __attribute__((ext_vector_type(8)));
typedef float  f32x4  __attribute__((ext_vector_type(4)));
typedef float  f32x2  __attribute__((ext_vector_type(2)));
typedef float  f32x16 __attribute__((ext_vector_type(16)));
typedef int    i32x4  __attribute__((ext_vector_type(4)));

// paired gelu: per-component op sequence identical to the R2/R5-proven scalar path
// (pk ops are per-component IEEE; __expf/rcp stay scalar per component)
__device__ __forceinline__ f32x2 gelu2(f32x2 x) {
    f32x2 x2 = x * x;                               // v_pk_mul_f32
    f32x2 t  = x2 * 0.044715f + 1.0f;               // v_pk_fma_f32, == fmaf(0.044715,x2,1)
    f32x2 a  = (x * -1.5957691216057308f) * t;      // (-c*x)*t, same assoc as scalar
    f32x2 e  = { __expf(a.x), __expf(a.y) };
    f32x2 d  = e + 1.0f;                            // v_pk_add_f32
    f32x2 r  = { __builtin_amdgcn_rcpf(d.x), __builtin_amdgcn_rcpf(d.y) };
    return x * r;                                   // v_pk_mul_f32
}

// two scalar RNE casts + bit assembly (value-identical to scalar stores)
__device__ __forceinline__ unsigned int pack2bf(float a, float b) {
    unsigned short ua = __builtin_bit_cast(unsigned short, (__bf16)a);
    unsigned short ub = __builtin_bit_cast(unsigned short, (__bf16)b);
    return (unsigned int)ua | ((unsigned int)ub << 16);
}

// w2t[u][k] = W2[k][u]  (bf16, K-contiguous per output column), 32768 elems
// w3t[d][u] = W3[u][d] for d<3 else 0 (bf16, padded to 32 rows), 8192 elems
__global__ void prep_weights(const float* __restrict__ W2, const float* __restrict__ W3,
                             __bf16* __restrict__ w2t, __bf16* __restrict__ w3t) {
    int idx = blockIdx.x * 256 + threadIdx.x;
    if (idx < 128 * 256) {
        int k = idx >> 8;
        int u = idx & 255;
        w2t[u * 128 + k] = (__bf16)W2[idx];
    } else if (idx < 128 * 256 + 32 * 256) {
        int t = idx - 128 * 256;
        int d = t >> 8;
        int u = t & 255;
        w3t[t] = (__bf16)(d < 3 ? W3[u * 3 + d] : 0.0f);
    }
}

__launch_bounds__(256, 4)
__global__ void edge_mlp(const float* __restrict__ y, const float* __restrict__ x,
                         const float* __restrict__ fy,
                         const int* __restrict__ nbr, const int* __restrict__ xidx,
                         const float* __restrict__ W1, const float* __restrict__ b1,
                         const __bf16* __restrict__ w2t, const float* __restrict__ b2,
                         const __bf16* __restrict__ w3t, const float* __restrict__ b3,
                         float* __restrict__ out, int E) {
    __shared__ __attribute__((aligned(16))) __bf16 g2s[64 * 128];  // h1 tile only, 16 KB
    __shared__ __attribute__((aligned(16))) float rels4[64][4];    // .w unused
    __shared__ float fys[64][3];
    __shared__ int   is[64];
    __shared__ float b2s[256];
    __shared__ float out3w[4][64][3];
    __shared__ float msg3[64][3];

    const int tid  = threadIdx.x;
    const int base = blockIdx.x * 64;

    // ---- stage edge tile + b2 ----
    if (tid < 64) {
        int g = base + tid;
        if (g < E) {
            int j = nbr[g];
            int i = xidx[g];
            is[tid] = i;
            f32x4 rr = { y[j*3+0] - x[i*3+0],
                         y[j*3+1] - x[i*3+1],
                         y[j*3+2] - x[i*3+2], 0.0f };
            *(f32x4*)&rels4[tid][0] = rr;
            fys[tid][0] = fy[j*3+0];
            fys[tid][1] = fy[j*3+1];
            fys[tid][2] = fy[j*3+2];
        } else {
            is[tid] = -1;
            *(f32x4*)&rels4[tid][0] = (f32x4){0.0f, 0.0f, 0.0f, 0.0f};
            fys[tid][0] = fys[tid][1] = fys[tid][2] = 0.0f;
        }
    }
    b2s[tid] = b2[tid];
    __syncthreads();

    // ---- layer 1: h1 = gelu(rel @ W1 + b1) -> A-tile (swizzled bf16) ----
    // paired gelu evaluation; rels read as one ds_read_b128 per edge
    {
        int u  = tid & 127;           // constant per thread
        int e0 = tid >> 7;
        float w0 = W1[u], w1 = W1[128 + u], w2 = W1[256 + u], bb = b1[u];
        #pragma unroll
        for (int r = 0; r < 32; r += 2) {
            int ea = e0 + 2 * r;
            int eb = ea + 2;
            f32x4 ra = *(const f32x4*)&rels4[ea][0];
            f32x4 rb = *(const f32x4*)&rels4[eb][0];
            float prea = fmaf(ra.x, w0, fmaf(ra.y, w1, fmaf(ra.z, w2, bb)));
            float preb = fmaf(rb.x, w0, fmaf(rb.y, w1, fmaf(rb.z, w2, bb)));
            f32x2 g = gelu2((f32x2){prea, preb});
            g2s[ea * 128 + (u ^ ((ea & 7) << 3))] = (__bf16)g.x;
            g2s[eb * 128 + (u ^ ((eb & 7) << 3))] = (__bf16)g.y;
        }
    }
    __syncthreads();

    // ---- layer 2 MFMA (operand-swapped, 32x32x16), ut2-sliced to cap live regs ----
    // wave w owns u in [64w, 64w+64); slice ut2 covers u-rows [(2w+ut2)*32, +32)
    const int w    = tid >> 6;
    const int lane = tid & 63;
    const int l31  = lane & 31;
    const int b    = lane >> 5;

    unsigned int pk[2][2][8];   // [ut2][et2][word]; filled slice-by-slice

    #pragma unroll
    for (int ut2 = 0; ut2 < 2; ++ut2) {
        f32x16 acc[2];   // [et2] — lifetime limited to this slice
        #pragma unroll
        for (int et2 = 0; et2 < 2; ++et2)
            #pragma unroll
            for (int q = 0; q < 16; ++q)
                acc[et2][q] = 0.0f;

        #pragma unroll
        for (int kt = 0; kt < 8; ++kt) {
            int kc = kt * 16 + b * 8;
            bf16x8 bfrg[2];
            #pragma unroll
            for (int et2 = 0; et2 < 2; ++et2) {
                int row = et2 * 32 + l31;                       // row = edge e (B-col)
                bfrg[et2] = *(const bf16x8*)&g2s[row * 128 + (kc ^ ((row & 7) << 3))];
            }
            int u = (2 * w + ut2) * 32 + l31;                   // A-row = u
            bf16x8 afrg = *(const bf16x8*)&w2t[u * 128 + kc];   // L2-resident
            #pragma unroll
            for (int et2 = 0; et2 < 2; ++et2)
                acc[et2] = __builtin_amdgcn_mfma_f32_32x32x16_bf16(
                    afrg, bfrg[et2], acc[et2], 0, 0, 0);
        }

        // epilogue in-register: g2 = gelu(h2 + b2), pack to bf16 pairs (paired gelu)
        // C layout (32x32): col=e=l31, row u_off = (reg&3) + 8*(reg>>2) + 4*b
        int u0 = (2 * w + ut2) * 32 + 4 * b;
        f32x4 b2q[4];
        #pragma unroll
        for (int g = 0; g < 4; ++g)
            b2q[g] = *(const f32x4*)&b2s[u0 + 8 * g];
        #pragma unroll
        for (int et2 = 0; et2 < 2; ++et2) {
            #pragma unroll
            for (int g = 0; g < 4; ++g) {
                f32x2 s01 = { acc[et2][4*g+0] + b2q[g][0], acc[et2][4*g+1] + b2q[g][1] };
                f32x2 s23 = { acc[et2][4*g+2] + b2q[g][2], acc[et2][4*g+3] + b2q[g][3] };
                f32x2 g01 = gelu2(s01);
                f32x2 g23 = gelu2(s23);
                pk[ut2][et2][2*g+0] = pack2bf(g01.x, g01.y);
                pk[ut2][et2][2*g+1] = pack2bf(g23.x, g23.y);
            }
        }
    }
    // no barrier: g2s is never overwritten

    // ---- layer 3 MFMA (32x32x16): C2[d][e] partial over wave's u-slice ----
    // B-frag assembled from pk; half-wave exchange via permlane32_swap builtin
    // (new_dst[l>=32]=src[l-32], new_src[l<32]=dst[l+32]  =>  (f0,f2)=swap(w0,w2))
    f32x16 acc3[2];
    #pragma unroll
    for (int et2 = 0; et2 < 2; ++et2)
        #pragma unroll
        for (int q = 0; q < 16; ++q)
            acc3[et2][q] = 0.0f;

    #pragma unroll
    for (int kt = 0; kt < 4; ++kt) {
        const int ut2 = kt >> 1, ki = kt & 1;
        bf16x8 a3 = *(const bf16x8*)&w3t[l31 * 256 + w * 64 + kt * 16 + b * 8];
        #pragma unroll
        for (int et2 = 0; et2 < 2; ++et2) {
            int w0_ = (int)pk[ut2][et2][4*ki + 0];
            int w1_ = (int)pk[ut2][et2][4*ki + 1];
            int w2_ = (int)pk[ut2][et2][4*ki + 2];
            int w3_ = (int)pk[ut2][et2][4*ki + 3];
            auto p02 = __builtin_amdgcn_permlane32_swap(w0_, w2_, false, false);
            auto p13 = __builtin_amdgcn_permlane32_swap(w1_, w3_, false, false);
            i32x4 fri = { static_cast<int>(p02[0]), static_cast<int>(p13[0]),
                          static_cast<int>(p02[1]), static_cast<int>(p13[1]) };
            bf16x8 bfr = __builtin_bit_cast(bf16x8, fri);
            acc3[et2] = __builtin_amdgcn_mfma_f32_32x32x16_bf16(a3, bfr, acc3[et2], 0, 0, 0);
        }
    }

    // valid outputs: rows d = reg (<3) for b==0 lanes; e = et2*32 + l31
    if (b == 0) {
        #pragma unroll
        for (int et2 = 0; et2 < 2; ++et2) {
            int e = et2 * 32 + l31;
            out3w[w][e][0] = acc3[et2][0];
            out3w[w][e][1] = acc3[et2][1];
            out3w[w][e][2] = acc3[et2][2];
        }
    }
    __syncthreads();

    // ---- combine wave partials, apply b3 and f_y ----
    if (tid < 192) {
        int e = tid / 3, d = tid - 3 * (tid / 3);
        float s = out3w[0][e][d] + out3w[1][e][d] + out3w[2][e][d] + out3w[3][e][d];
        msg3[e][d] = (s + b3[d]) * fys[e][d];
    }
    __syncthreads();

    // ---- segmented sum over sorted x_index: one atomic triple per distinct i ----
    if (tid < 64) {
        int i = is[tid];
        bool leader = (i >= 0) && (tid == 0 || is[tid - 1] != i);
        if (leader) {
            float s0 = 0.0f, s1 = 0.0f, s2 = 0.0f;
            int j = tid;
            while (j < 64 && is[j] == i) {
                s0 += msg3[j][0]; s1 += msg3[j][1]; s2 += msg3[j][2]; ++j;
            }
            unsafeAtomicAdd(&out[i*3+0], s0);
            unsafeAtomicAdd(&out[i*3+1], s1);
            unsafeAtomicAdd(&out[i*3+2], s2);
        }
    }
}

// out[i] /= max(cnt_i, 1); cnt via binary search on sorted x_index
__global__ void finalize_div(float* __restrict__ out, const int* __restrict__ xidx,
                             int E, int nx) {
    int i = blockIdx.x * blockDim.x + threadIdx.x;
    if (i >= nx) return;
    int lo = 0, hi = E;
    while (lo < hi) { int mid = (lo + hi) >> 1; if (xidx[mid] < i) lo = mid + 1; else hi = mid; }
    int start = lo;
    hi = E;
    while (lo < hi) { int mid = (lo + hi) >> 1; if (xidx[mid] < i + 1) lo = mid + 1; else hi = mid; }
    int cnt = lo - start;
    float inv = 1.0f / (float)(cnt > 1 ? cnt : 1);
    out[i*3+0] *= inv;
    out[i*3+1] *= inv;
    out[i*3+2] *= inv;
}

extern "C" void kernel_launch(void* const* d_in, const int* in_sizes, int n_in,
                              void* d_out, int out_size, void* d_ws, size_t ws_size,
                              hipStream_t stream) {
    const float* y   = (const float*)d_in[0];
    const float* x   = (const float*)d_in[1];
    const float* fyp = (const float*)d_in[2];
    const int*   nbr = (const int*)d_in[3];
    const int*   xix = (const int*)d_in[4];
    const float* W1  = (const float*)d_in[5];
    const float* b1  = (const float*)d_in[6];
    const float* W2  = (const float*)d_in[7];
    const float* b2  = (const float*)d_in[8];
    const float* W3  = (const float*)d_in[9];
    const float* b3  = (const float*)d_in[10];
    float* out = (float*)d_out;

    int E  = in_sizes[3];
    int nx = in_sizes[1] / 3;
    __bf16* w2t = (__bf16*)d_ws;                       // 32768 bf16 = 64KB
    __bf16* w3t = (__bf16*)((char*)d_ws + 65536);      // 8192 bf16 = 16KB

    hipMemsetAsync(d_out, 0, (size_t)out_size * sizeof(float), stream);
    prep_weights<<<160, 256, 0, stream>>>(W2, W3, w2t, w3t);

    int ntiles = (E + 63) / 64;
    edge_mlp<<<ntiles, 256, 0, stream>>>(y, x, fyp, nbr, xix, W1, b1, w2t, b2, w3t, b3, out, E);

    finalize_div<<<(nx + 255) / 256, 256, 0, stream>>>(out, xix, E, nx);
}